// Round 1
// baseline (739.077 us; speedup 1.0000x reference)
//
#include <hip/hip_runtime.h>
#include <math.h>

#define HI 256
#define WI 256
#define NIMG 128          // B*S
#define NP 68             // landmarks
#define NT 16             // 4x4 tiles of 16x16 outputs per 64x64 heatmap
#define NPAIR 120         // B*(S-1)
#define K_LK 289          // 17x17 window

// ---------------------------------------------------------------------------
// Kernel 1: gray = mean over channels.  in [128][3][256][256] -> gray [128][256][256]
// ---------------------------------------------------------------------------
__global__ __launch_bounds__(256) void k_gray(const float* __restrict__ in,
                                              float* __restrict__ gray) {
    const int QT = HI * WI / 4;            // float4 per image-plane
    const int total = NIMG * QT;
    const float4* in4 = (const float4*)in;
    float4* g4 = (float4*)gray;
    const float kk = 1.0f / 3.0f;
    for (int idx = blockIdx.x * 256 + threadIdx.x; idx < total; idx += gridDim.x * 256) {
        int img = idx / QT;
        int off = idx - img * QT;
        const float4* base = in4 + (size_t)img * 3 * QT + off;
        float4 a = base[0];
        float4 b = base[QT];
        float4 c = base[2 * QT];
        float4 o;
        o.x = (a.x + b.x + c.x) * kk;
        o.y = (a.y + b.y + c.y) * kk;
        o.z = (a.z + b.z + c.z) * kk;
        o.w = (a.w + b.w + c.w) * kk;
        g4[idx] = o;
    }
}

// ---------------------------------------------------------------------------
// Kernel 2: conv 7x7 stride 4 'SAME' (pad_lo=1) for all 68 filters over a
// 16x16 output tile, then per-tile online-softmax stats (m, s, sx, sy).
// grid (16, 128), block 256.
// Thread tile: 4 consecutive-x pixels x 17 filters. Wave w handles filter
// chunk w (p = w*17 .. w*17+16) and all 256 pixels of the tile.
// stats layout: [n][p][tile][4]
// ---------------------------------------------------------------------------
__global__ __launch_bounds__(256) void k_conv(const float* __restrict__ in,
                                              const float* __restrict__ dw,
                                              float* __restrict__ stats) {
    const int tile = blockIdx.x;
    const int n = blockIdx.y;
    const int ty0 = (tile >> 2) * 16;
    const int tx0 = (tile & 3) * 16;
    const int tid = threadIdx.x;
    const int pc_raw = tid >> 6;                 // wave id = filter chunk
    const int pc = __builtin_amdgcn_readfirstlane(pc_raw);  // force SGPR
    const int g = tid & 63;                      // lane
    const int py = g >> 2;                       // pixel row in tile (0..15)
    const int xg = g & 3;                        // x-group (4 px each)

    __shared__ float lds[16 * 67];

    float acc[17][4];
#pragma unroll
    for (int a = 0; a < 17; ++a)
#pragma unroll
        for (int b = 0; b < 4; ++b) acc[a][b] = 0.0f;

    const float* img = in + (size_t)n * 3 * HI * WI;

#pragma unroll 1
    for (int c = 0; c < 3; ++c) {
#pragma unroll 1
        for (int ky = 0; ky < 7; ++ky) {
            __syncthreads();
            // stage 16 input rows x 67 cols for this (c, ky)
            for (int idx = tid; idx < 16 * 67; idx += 256) {
                int r = idx / 67;
                int x = idx - r * 67;
                int R = 4 * ty0 + 4 * r + ky - 1;
                int C = 4 * tx0 + x - 1;
                float v = 0.0f;
                if ((unsigned)R < HI && (unsigned)C < WI)
                    v = img[(size_t)c * HI * WI + R * WI + C];
                lds[idx] = v;
            }
            __syncthreads();

            float rv[20];
#pragma unroll
            for (int m = 0; m < 20; ++m)
                rv[m] = lds[py * 67 + 16 * xg + m];

            const float* wbase = dw + c * 49 + ky * 7;   // + p*147 + kx
#pragma unroll
            for (int pi = 0; pi < 17; ++pi) {
                const float* wp = wbase + (pc * 17 + pi) * 147;
#pragma unroll
                for (int kx = 0; kx < 7; ++kx) {
                    float wv = wp[kx];
#pragma unroll
                    for (int j = 0; j < 4; ++j)
                        acc[pi][j] = fmaf(wv, rv[4 * j + kx], acc[pi][j]);
                }
            }
        }
    }

    // epilogue: per-filter wave reduction -> online-softmax tile stats
#pragma unroll 1
    for (int pi = 0; pi < 17; ++pi) {
        float m = fmaxf(fmaxf(acc[pi][0], acc[pi][1]), fmaxf(acc[pi][2], acc[pi][3]));
        for (int mm = 32; mm; mm >>= 1) m = fmaxf(m, __shfl_xor(m, mm, 64));
        float s = 0.0f, sx = 0.0f, sy = 0.0f;
#pragma unroll
        for (int j = 0; j < 4; ++j) {
            float e = expf(acc[pi][j] - m);
            s += e;
            sx += e * (float)(tx0 + 4 * xg + j);
            sy += e * (float)(ty0 + py);
        }
        for (int mm = 32; mm; mm >>= 1) {
            s += __shfl_xor(s, mm, 64);
            sx += __shfl_xor(sx, mm, 64);
            sy += __shfl_xor(sy, mm, 64);
        }
        if (g == 0) {
            int p = pc * 17 + pi;
            float4* o = (float4*)(stats + (((size_t)n * NP + p) * NT + tile) * 4);
            *o = make_float4(m, s, sx, sy);
        }
    }
}

// ---------------------------------------------------------------------------
// Kernel 3: merge 16 tile stats per (n,p) -> locs (soft-argmax * 4)
// ---------------------------------------------------------------------------
__global__ __launch_bounds__(256) void k_centroid(const float* __restrict__ stats,
                                                  float* __restrict__ locs) {
    int idx = blockIdx.x * 256 + threadIdx.x;   // n*68 + p
    if (idx >= NIMG * NP) return;
    const float4* st = (const float4*)(stats + (size_t)idx * NT * 4);
    float M = -3.4e38f, S = 0.0f, SX = 0.0f, SY = 0.0f;
#pragma unroll
    for (int t = 0; t < NT; ++t) {
        float4 v = st[t];
        float m2 = fmaxf(M, v.x);
        float e0 = expf(M - m2);
        float e1 = expf(v.x - m2);
        S = S * e0 + v.y * e1;
        SX = SX * e0 + v.z * e1;
        SY = SY * e0 + v.w * e1;
        M = m2;
    }
    locs[idx * 2 + 0] = SX / S * 4.0f;
    locs[idx * 2 + 1] = SY / S * 4.0f;
}

// ---------------------------------------------------------------------------
// Kernel 4: iterative Lucas-Kanade, one wave per (pair, point, variant)
// ---------------------------------------------------------------------------
__device__ __forceinline__ float bil(const float* __restrict__ img, float x, float y) {
    float x0f = floorf(x), y0f = floorf(y);
    float wx = x - x0f, wy = y - y0f;
    int x0 = (int)x0f, y0 = (int)y0f;
    int x0i = min(max(x0, 0), WI - 1);
    int x1i = min(x0i + 1, WI - 1);
    int y0i = min(max(y0, 0), HI - 1);
    int y1i = min(y0i + 1, HI - 1);
    float v00 = img[y0i * WI + x0i];
    float v01 = img[y0i * WI + x1i];
    float v10 = img[y1i * WI + x0i];
    float v11 = img[y1i * WI + x1i];
    return v00 * (1.0f - wx) * (1.0f - wy) + v01 * wx * (1.0f - wy)
         + v10 * (1.0f - wx) * wy + v11 * wx * wy;
}

__device__ void lk_track(const float* __restrict__ I, const float* __restrict__ J,
                         int lane, float x, float y, float& ox_, float& oy_) {
    float dxo[5], dyo[5];
    bool valid[5];
    float T[5], Gx[5], Gy[5];
    float a11 = 0.0f, a12 = 0.0f, a22 = 0.0f;
#pragma unroll
    for (int i = 0; i < 5; ++i) {
        int k = lane + 64 * i;
        valid[i] = (k < K_LK);
        int kk = valid[i] ? k : 0;
        dxo[i] = (float)(kk % 17 - 8);
        dyo[i] = (float)(kk / 17 - 8);
        float fx = x + dxo[i];
        float fy = y + dyo[i];
        float t = bil(I, fx, fy);
        float gx = (bil(I, fx + 1.0f, fy) - bil(I, fx - 1.0f, fy)) * 0.5f;
        float gy = (bil(I, fx, fy + 1.0f) - bil(I, fx, fy - 1.0f)) * 0.5f;
        if (!valid[i]) { t = 0.0f; gx = 0.0f; gy = 0.0f; }
        T[i] = t; Gx[i] = gx; Gy[i] = gy;
        a11 += gx * gx; a12 += gx * gy; a22 += gy * gy;
    }
    for (int m = 32; m; m >>= 1) {
        a11 += __shfl_xor(a11, m, 64);
        a12 += __shfl_xor(a12, m, 64);
        a22 += __shfl_xor(a22, m, 64);
    }
    a11 += 1e-6f;
    a22 += 1e-6f;
    float det = a11 * a22 - a12 * a12;
    float i11 = a22 / det, i12 = -a12 / det, i22 = a11 / det;
    float px = x, py = y;
#pragma unroll 1
    for (int s = 0; s < 10; ++s) {
        float bx = 0.0f, by = 0.0f;
#pragma unroll
        for (int i = 0; i < 5; ++i) {
            float e = T[i] - bil(J, px + dxo[i], py + dyo[i]);
            bx += Gx[i] * e;
            by += Gy[i] * e;
        }
        for (int m = 32; m; m >>= 1) {
            bx += __shfl_xor(bx, m, 64);
            by += __shfl_xor(by, m, 64);
        }
        px += i11 * bx + i12 * by;
        py += i12 * bx + i22 * by;
    }
    ox_ = px;
    oy_ = py;
}

__global__ __launch_bounds__(256) void k_lk(const float* __restrict__ gray,
                                            const float* __restrict__ locs,
                                            float* __restrict__ out_next,
                                            float* __restrict__ out_fb,
                                            float* __restrict__ out_back) {
    int wid = (blockIdx.x * 256 + threadIdx.x) >> 6;
    int lane = threadIdx.x & 63;
    int variant = wid / (NPAIR * NP);
    int r = wid - variant * (NPAIR * NP);
    int pr = r / NP;
    int j = r - pr * NP;
    int b = pr / 15;
    int t = pr - b * 15;
    int n0 = b * 16 + t;
    const float* I = gray + (size_t)n0 * HI * WI;
    const float* J = gray + (size_t)(n0 + 1) * HI * WI;
    int o = (pr * NP + j) * 2;
    if (variant == 0) {
        float x = locs[(n0 * NP + j) * 2 + 0];
        float y = locs[(n0 * NP + j) * 2 + 1];
        float nx, ny;
        lk_track(I, J, lane, x, y, nx, ny);
        if (lane == 0) { out_next[o] = nx; out_next[o + 1] = ny; }
        float fx, fy;
        lk_track(J, I, lane, nx, ny, fx, fy);
        if (lane == 0) { out_fb[o] = fx; out_fb[o + 1] = fy; }
    } else {
        float x = locs[((n0 + 1) * NP + j) * 2 + 0];
        float y = locs[((n0 + 1) * NP + j) * 2 + 1];
        float bx, by;
        lk_track(J, I, lane, x, y, bx, by);
        if (lane == 0) { out_back[o] = bx; out_back[o + 1] = by; }
    }
}

// ---------------------------------------------------------------------------
extern "C" void kernel_launch(void* const* d_in, const int* in_sizes, int n_in,
                              void* d_out, int out_size, void* d_ws, size_t ws_size,
                              hipStream_t stream) {
    const float* inputs = (const float*)d_in[0];
    const float* det_w  = (const float*)d_in[1];
    // det_b (d_in[2]) is softmax-shift-invariant -> unused
    float* out = (float*)d_out;

    float* gray  = (float*)d_ws;                                  // 128*256*256 f32 = 32 MiB
    float* stats = (float*)((char*)d_ws + (size_t)NIMG * HI * WI * 4); // 128*68*16*4 f32

    float* locs   = out;                    // [8,16,68,2]  = 17408
    float* next_p = out + 17408;            // [8,15,68,2]  = 16320
    float* fb_p   = out + 33728;
    float* back_p = out + 50048;

    hipLaunchKernelGGL(k_gray, dim3(2048), dim3(256), 0, stream, inputs, gray);
    hipLaunchKernelGGL(k_conv, dim3(NT, NIMG), dim3(256), 0, stream, inputs, det_w, stats);
    hipLaunchKernelGGL(k_centroid, dim3((NIMG * NP + 255) / 256), dim3(256), 0, stream,
                       stats, locs);
    hipLaunchKernelGGL(k_lk, dim3(2 * NPAIR * NP / 4), dim3(256), 0, stream,
                       gray, locs, next_p, fb_p, back_p);
}

// Round 2
// 417.176 us; speedup vs baseline: 1.7716x; 1.7716x over previous
//
#include <hip/hip_runtime.h>
#include <math.h>

#define HI 256
#define WI 256
#define NIMG 128          // B*S
#define NP 68             // landmarks
#define NT 16             // 4x4 tiles of 16x16 outputs per 64x64 heatmap
#define NPAIR 120         // B*(S-1)
#define K_LK 289          // 17x17 window

// ---------------------------------------------------------------------------
// Kernel 1: gray = mean over channels.  in [128][3][256][256] -> gray [128][256][256]
// ---------------------------------------------------------------------------
__global__ __launch_bounds__(256) void k_gray(const float* __restrict__ in,
                                              float* __restrict__ gray) {
    const int QT = HI * WI / 4;            // float4 per image-plane
    const int total = NIMG * QT;
    const float4* in4 = (const float4*)in;
    float4* g4 = (float4*)gray;
    const float kk = 1.0f / 3.0f;
    for (int idx = blockIdx.x * 256 + threadIdx.x; idx < total; idx += gridDim.x * 256) {
        int img = idx / QT;
        int off = idx - img * QT;
        const float4* base = in4 + (size_t)img * 3 * QT + off;
        float4 a = base[0];
        float4 b = base[QT];
        float4 c = base[2 * QT];
        float4 o;
        o.x = (a.x + b.x + c.x) * kk;
        o.y = (a.y + b.y + c.y) * kk;
        o.z = (a.z + b.z + c.z) * kk;
        o.w = (a.w + b.w + c.w) * kk;
        g4[idx] = o;
    }
}

// ---------------------------------------------------------------------------
// Kernel 2: conv 7x7 stride 4 'SAME' (pad_lo=1) for all 68 filters over a
// 16x16 output tile, then per-tile online-softmax stats (m, s, sx, sy).
// grid (16, 128), block 256.
// Thread tile: 4 consecutive-x pixels x 17 filters. Wave w handles filter
// chunk w (p = w*17 .. w*17+16) and all 256 pixels of the tile.
// stats layout: [n][p][tile][4]
// NOTE: epilogue MUST be fully unrolled — runtime-indexed acc[pi] sends the
// whole accumulator array to scratch (round 1: VGPR=56, WRITE_SIZE=3GB, 550us).
// ---------------------------------------------------------------------------
__global__ __launch_bounds__(256) void k_conv(const float* __restrict__ in,
                                              const float* __restrict__ dw,
                                              float* __restrict__ stats) {
    const int tile = blockIdx.x;
    const int n = blockIdx.y;
    const int ty0 = (tile >> 2) * 16;
    const int tx0 = (tile & 3) * 16;
    const int tid = threadIdx.x;
    const int pc_raw = tid >> 6;                 // wave id = filter chunk
    const int pc = __builtin_amdgcn_readfirstlane(pc_raw);  // force SGPR
    const int g = tid & 63;                      // lane
    const int py = g >> 2;                       // pixel row in tile (0..15)
    const int xg = g & 3;                        // x-group (4 px each)

    __shared__ float lds[16 * 67];               // stride 67 (odd): b32 reads 2-way = free

    float acc[17][4];
#pragma unroll
    for (int a = 0; a < 17; ++a)
#pragma unroll
        for (int b = 0; b < 4; ++b) acc[a][b] = 0.0f;

    const float* img = in + (size_t)n * 3 * HI * WI;

#pragma unroll 1
    for (int c = 0; c < 3; ++c) {
#pragma unroll 1
        for (int ky = 0; ky < 7; ++ky) {
            __syncthreads();
            // stage 16 input rows x 67 cols for this (c, ky)
            for (int idx = tid; idx < 16 * 67; idx += 256) {
                int r = idx / 67;
                int x = idx - r * 67;
                int R = 4 * ty0 + 4 * r + ky - 1;
                int C = 4 * tx0 + x - 1;
                float v = 0.0f;
                if ((unsigned)R < HI && (unsigned)C < WI)
                    v = img[(size_t)c * HI * WI + R * WI + C];
                lds[idx] = v;
            }
            __syncthreads();

            float rv[20];
#pragma unroll
            for (int m = 0; m < 20; ++m)
                rv[m] = lds[py * 67 + 16 * xg + m];

            const float* wbase = dw + c * 49 + ky * 7;   // + p*147 + kx
#pragma unroll
            for (int pi = 0; pi < 17; ++pi) {
                const float* wp = wbase + (pc * 17 + pi) * 147;
#pragma unroll
                for (int kx = 0; kx < 7; ++kx) {
                    float wv = wp[kx];
#pragma unroll
                    for (int j = 0; j < 4; ++j)
                        acc[pi][j] = fmaf(wv, rv[4 * j + kx], acc[pi][j]);
                }
            }
        }
    }

    // epilogue: per-filter wave reduction -> online-softmax tile stats
    // FULLY UNROLLED so acc[][] stays compile-time-indexed (registers).
#pragma unroll
    for (int pi = 0; pi < 17; ++pi) {
        float m = fmaxf(fmaxf(acc[pi][0], acc[pi][1]), fmaxf(acc[pi][2], acc[pi][3]));
        for (int mm = 32; mm; mm >>= 1) m = fmaxf(m, __shfl_xor(m, mm, 64));
        float s = 0.0f, sx = 0.0f, sy = 0.0f;
#pragma unroll
        for (int j = 0; j < 4; ++j) {
            float e = expf(acc[pi][j] - m);
            s += e;
            sx += e * (float)(tx0 + 4 * xg + j);
            sy += e * (float)(ty0 + py);
        }
        for (int mm = 32; mm; mm >>= 1) {
            s += __shfl_xor(s, mm, 64);
            sx += __shfl_xor(sx, mm, 64);
            sy += __shfl_xor(sy, mm, 64);
        }
        if (g == 0) {
            int p = pc * 17 + pi;
            float4* o = (float4*)(stats + (((size_t)n * NP + p) * NT + tile) * 4);
            *o = make_float4(m, s, sx, sy);
        }
    }
}

// ---------------------------------------------------------------------------
// Kernel 3: merge 16 tile stats per (n,p) -> locs (soft-argmax * 4)
// ---------------------------------------------------------------------------
__global__ __launch_bounds__(256) void k_centroid(const float* __restrict__ stats,
                                                  float* __restrict__ locs) {
    int idx = blockIdx.x * 256 + threadIdx.x;   // n*68 + p
    if (idx >= NIMG * NP) return;
    const float4* st = (const float4*)(stats + (size_t)idx * NT * 4);
    float M = -3.4e38f, S = 0.0f, SX = 0.0f, SY = 0.0f;
#pragma unroll
    for (int t = 0; t < NT; ++t) {
        float4 v = st[t];
        float m2 = fmaxf(M, v.x);
        float e0 = expf(M - m2);
        float e1 = expf(v.x - m2);
        S = S * e0 + v.y * e1;
        SX = SX * e0 + v.z * e1;
        SY = SY * e0 + v.w * e1;
        M = m2;
    }
    locs[idx * 2 + 0] = SX / S * 4.0f;
    locs[idx * 2 + 1] = SY / S * 4.0f;
}

// ---------------------------------------------------------------------------
// Kernel 4: iterative Lucas-Kanade, one wave per (pair, point, variant)
// ---------------------------------------------------------------------------
__device__ __forceinline__ float bil(const float* __restrict__ img, float x, float y) {
    float x0f = floorf(x), y0f = floorf(y);
    float wx = x - x0f, wy = y - y0f;
    int x0 = (int)x0f, y0 = (int)y0f;
    int x0i = min(max(x0, 0), WI - 1);
    int x1i = min(x0i + 1, WI - 1);
    int y0i = min(max(y0, 0), HI - 1);
    int y1i = min(y0i + 1, HI - 1);
    float v00 = img[y0i * WI + x0i];
    float v01 = img[y0i * WI + x1i];
    float v10 = img[y1i * WI + x0i];
    float v11 = img[y1i * WI + x1i];
    return v00 * (1.0f - wx) * (1.0f - wy) + v01 * wx * (1.0f - wy)
         + v10 * (1.0f - wx) * wy + v11 * wx * wy;
}

__device__ void lk_track(const float* __restrict__ I, const float* __restrict__ J,
                         int lane, float x, float y, float& ox_, float& oy_) {
    float dxo[5], dyo[5];
    bool valid[5];
    float T[5], Gx[5], Gy[5];
    float a11 = 0.0f, a12 = 0.0f, a22 = 0.0f;
#pragma unroll
    for (int i = 0; i < 5; ++i) {
        int k = lane + 64 * i;
        valid[i] = (k < K_LK);
        int kk = valid[i] ? k : 0;
        dxo[i] = (float)(kk % 17 - 8);
        dyo[i] = (float)(kk / 17 - 8);
        float fx = x + dxo[i];
        float fy = y + dyo[i];
        float t = bil(I, fx, fy);
        float gx = (bil(I, fx + 1.0f, fy) - bil(I, fx - 1.0f, fy)) * 0.5f;
        float gy = (bil(I, fx, fy + 1.0f) - bil(I, fx, fy - 1.0f)) * 0.5f;
        if (!valid[i]) { t = 0.0f; gx = 0.0f; gy = 0.0f; }
        T[i] = t; Gx[i] = gx; Gy[i] = gy;
        a11 += gx * gx; a12 += gx * gy; a22 += gy * gy;
    }
    for (int m = 32; m; m >>= 1) {
        a11 += __shfl_xor(a11, m, 64);
        a12 += __shfl_xor(a12, m, 64);
        a22 += __shfl_xor(a22, m, 64);
    }
    a11 += 1e-6f;
    a22 += 1e-6f;
    float det = a11 * a22 - a12 * a12;
    float i11 = a22 / det, i12 = -a12 / det, i22 = a11 / det;
    float px = x, py = y;
#pragma unroll 1
    for (int s = 0; s < 10; ++s) {
        float bx = 0.0f, by = 0.0f;
#pragma unroll
        for (int i = 0; i < 5; ++i) {
            float e = T[i] - bil(J, px + dxo[i], py + dyo[i]);
            bx += Gx[i] * e;
            by += Gy[i] * e;
        }
        for (int m = 32; m; m >>= 1) {
            bx += __shfl_xor(bx, m, 64);
            by += __shfl_xor(by, m, 64);
        }
        px += i11 * bx + i12 * by;
        py += i12 * bx + i22 * by;
    }
    ox_ = px;
    oy_ = py;
}

__global__ __launch_bounds__(256) void k_lk(const float* __restrict__ gray,
                                            const float* __restrict__ locs,
                                            float* __restrict__ out_next,
                                            float* __restrict__ out_fb,
                                            float* __restrict__ out_back) {
    int wid = (blockIdx.x * 256 + threadIdx.x) >> 6;
    int lane = threadIdx.x & 63;
    int variant = wid / (NPAIR * NP);
    int r = wid - variant * (NPAIR * NP);
    int pr = r / NP;
    int j = r - pr * NP;
    int b = pr / 15;
    int t = pr - b * 15;
    int n0 = b * 16 + t;
    const float* I = gray + (size_t)n0 * HI * WI;
    const float* J = gray + (size_t)(n0 + 1) * HI * WI;
    int o = (pr * NP + j) * 2;
    if (variant == 0) {
        float x = locs[(n0 * NP + j) * 2 + 0];
        float y = locs[(n0 * NP + j) * 2 + 1];
        float nx, ny;
        lk_track(I, J, lane, x, y, nx, ny);
        if (lane == 0) { out_next[o] = nx; out_next[o + 1] = ny; }
        float fx, fy;
        lk_track(J, I, lane, nx, ny, fx, fy);
        if (lane == 0) { out_fb[o] = fx; out_fb[o + 1] = fy; }
    } else {
        float x = locs[((n0 + 1) * NP + j) * 2 + 0];
        float y = locs[((n0 + 1) * NP + j) * 2 + 1];
        float bx, by;
        lk_track(J, I, lane, x, y, bx, by);
        if (lane == 0) { out_back[o] = bx; out_back[o + 1] = by; }
    }
}

// ---------------------------------------------------------------------------
extern "C" void kernel_launch(void* const* d_in, const int* in_sizes, int n_in,
                              void* d_out, int out_size, void* d_ws, size_t ws_size,
                              hipStream_t stream) {
    const float* inputs = (const float*)d_in[0];
    const float* det_w  = (const float*)d_in[1];
    // det_b (d_in[2]) is softmax-shift-invariant -> unused
    float* out = (float*)d_out;

    float* gray  = (float*)d_ws;                                  // 128*256*256 f32 = 32 MiB
    float* stats = (float*)((char*)d_ws + (size_t)NIMG * HI * WI * 4); // 128*68*16*4 f32

    float* locs   = out;                    // [8,16,68,2]  = 17408
    float* next_p = out + 17408;            // [8,15,68,2]  = 16320
    float* fb_p   = out + 33728;
    float* back_p = out + 50048;

    hipLaunchKernelGGL(k_gray, dim3(2048), dim3(256), 0, stream, inputs, gray);
    hipLaunchKernelGGL(k_conv, dim3(NT, NIMG), dim3(256), 0, stream, inputs, det_w, stats);
    hipLaunchKernelGGL(k_centroid, dim3((NIMG * NP + 255) / 256), dim3(256), 0, stream,
                       stats, locs);
    hipLaunchKernelGGL(k_lk, dim3(2 * NPAIR * NP / 4), dim3(256), 0, stream,
                       gray, locs, next_p, fb_p, back_p);
}

// Round 3
// 304.623 us; speedup vs baseline: 2.4262x; 1.3695x over previous
//
#include <hip/hip_runtime.h>
#include <math.h>

#define HI 256
#define WI 256
#define NIMG 128          // B*S
#define NP 68             // landmarks
#define NT 16             // 4x4 tiles of 16x16 outputs per 64x64 heatmap
#define NPAIR 120         // B*(S-1)
#define K_LK 289          // 17x17 window

typedef float f4v __attribute__((ext_vector_type(4)));
typedef float f2v __attribute__((ext_vector_type(2)));
// under-aligned views: window offsets make these only 4B-aligned
typedef f4v __attribute__((aligned(4))) uf4;
typedef f2v __attribute__((aligned(4))) uf2;

// ---------------------------------------------------------------------------
// Kernel 1: gray = mean over channels.  in [128][3][256][256] -> gray [128][256][256]
// ---------------------------------------------------------------------------
__global__ __launch_bounds__(256) void k_gray(const float* __restrict__ in,
                                              float* __restrict__ gray) {
    const int QT = HI * WI / 4;            // float4 per image-plane
    const int total = NIMG * QT;
    const float4* in4 = (const float4*)in;
    float4* g4 = (float4*)gray;
    const float kk = 1.0f / 3.0f;
    for (int idx = blockIdx.x * 256 + threadIdx.x; idx < total; idx += gridDim.x * 256) {
        int img = idx / QT;
        int off = idx - img * QT;
        const float4* base = in4 + (size_t)img * 3 * QT + off;
        float4 a = base[0];
        float4 b = base[QT];
        float4 c = base[2 * QT];
        float4 o;
        o.x = (a.x + b.x + c.x) * kk;
        o.y = (a.y + b.y + c.y) * kk;
        o.z = (a.z + b.z + c.z) * kk;
        o.w = (a.w + b.w + c.w) * kk;
        g4[idx] = o;
    }
}

// ---------------------------------------------------------------------------
// Kernel 2: conv 7x7 stride 4 'SAME' (pad_lo=1) for all 68 filters over a
// 16x16 output tile, then per-tile online-softmax stats (m, s, sx, sy).
// grid (16, 128), block 256.
// NOTE: epilogue MUST be fully unrolled — runtime-indexed acc[pi] sends the
// whole accumulator array to scratch (round 1: VGPR=56, WRITE_SIZE=3GB, 550us).
// ---------------------------------------------------------------------------
__global__ __launch_bounds__(256) void k_conv(const float* __restrict__ in,
                                              const float* __restrict__ dw,
                                              float* __restrict__ stats) {
    const int tile = blockIdx.x;
    const int n = blockIdx.y;
    const int ty0 = (tile >> 2) * 16;
    const int tx0 = (tile & 3) * 16;
    const int tid = threadIdx.x;
    const int pc_raw = tid >> 6;                 // wave id = filter chunk
    const int pc = __builtin_amdgcn_readfirstlane(pc_raw);  // force SGPR
    const int g = tid & 63;                      // lane
    const int py = g >> 2;                       // pixel row in tile (0..15)
    const int xg = g & 3;                        // x-group (4 px each)

    __shared__ float lds[16 * 67];               // stride 67 (odd): b32 reads 2-way = free

    float acc[17][4];
#pragma unroll
    for (int a = 0; a < 17; ++a)
#pragma unroll
        for (int b = 0; b < 4; ++b) acc[a][b] = 0.0f;

    const float* img = in + (size_t)n * 3 * HI * WI;

#pragma unroll 1
    for (int c = 0; c < 3; ++c) {
#pragma unroll 1
        for (int ky = 0; ky < 7; ++ky) {
            __syncthreads();
            // stage 16 input rows x 67 cols for this (c, ky)
            for (int idx = tid; idx < 16 * 67; idx += 256) {
                int r = idx / 67;
                int x = idx - r * 67;
                int R = 4 * ty0 + 4 * r + ky - 1;
                int C = 4 * tx0 + x - 1;
                float v = 0.0f;
                if ((unsigned)R < HI && (unsigned)C < WI)
                    v = img[(size_t)c * HI * WI + R * WI + C];
                lds[idx] = v;
            }
            __syncthreads();

            float rv[20];
#pragma unroll
            for (int m = 0; m < 20; ++m)
                rv[m] = lds[py * 67 + 16 * xg + m];

            const float* wbase = dw + c * 49 + ky * 7;   // + p*147 + kx
#pragma unroll
            for (int pi = 0; pi < 17; ++pi) {
                const float* wp = wbase + (pc * 17 + pi) * 147;
#pragma unroll
                for (int kx = 0; kx < 7; ++kx) {
                    float wv = wp[kx];
#pragma unroll
                    for (int j = 0; j < 4; ++j)
                        acc[pi][j] = fmaf(wv, rv[4 * j + kx], acc[pi][j]);
                }
            }
        }
    }

    // epilogue: per-filter wave reduction -> online-softmax tile stats
    // FULLY UNROLLED so acc[][] stays compile-time-indexed (registers).
#pragma unroll
    for (int pi = 0; pi < 17; ++pi) {
        float m = fmaxf(fmaxf(acc[pi][0], acc[pi][1]), fmaxf(acc[pi][2], acc[pi][3]));
        for (int mm = 32; mm; mm >>= 1) m = fmaxf(m, __shfl_xor(m, mm, 64));
        float s = 0.0f, sx = 0.0f, sy = 0.0f;
#pragma unroll
        for (int j = 0; j < 4; ++j) {
            float e = expf(acc[pi][j] - m);
            s += e;
            sx += e * (float)(tx0 + 4 * xg + j);
            sy += e * (float)(ty0 + py);
        }
        for (int mm = 32; mm; mm >>= 1) {
            s += __shfl_xor(s, mm, 64);
            sx += __shfl_xor(sx, mm, 64);
            sy += __shfl_xor(sy, mm, 64);
        }
        if (g == 0) {
            int p = pc * 17 + pi;
            float4* o = (float4*)(stats + (((size_t)n * NP + p) * NT + tile) * 4);
            *o = make_float4(m, s, sx, sy);
        }
    }
}

// ---------------------------------------------------------------------------
// Kernel 3: merge 16 tile stats per (n,p) -> locs (soft-argmax * 4)
// ---------------------------------------------------------------------------
__global__ __launch_bounds__(256) void k_centroid(const float* __restrict__ stats,
                                                  float* __restrict__ locs) {
    int idx = blockIdx.x * 256 + threadIdx.x;   // n*68 + p
    if (idx >= NIMG * NP) return;
    const float4* st = (const float4*)(stats + (size_t)idx * NT * 4);
    float M = -3.4e38f, S = 0.0f, SX = 0.0f, SY = 0.0f;
#pragma unroll
    for (int t = 0; t < NT; ++t) {
        float4 v = st[t];
        float m2 = fmaxf(M, v.x);
        float e0 = expf(M - m2);
        float e1 = expf(v.x - m2);
        S = S * e0 + v.y * e1;
        SX = SX * e0 + v.z * e1;
        SY = SY * e0 + v.w * e1;
        M = m2;
    }
    locs[idx * 2 + 0] = SX / S * 4.0f;
    locs[idx * 2 + 1] = SY / S * 4.0f;
}

// ---------------------------------------------------------------------------
// Kernel 4: iterative Lucas-Kanade.
// Key structural fact: window offsets are INTEGERS, so the bilinear frac
// weights (wx, wy) are wave-uniform per track. Fast path (track fully
// interior, wave-uniform scalar branch): per-sample work collapses to small
// vector loads on the integer grid + FMA with shared weights. Boundary
// tracks fall back to the exact reference-style bil() path.
// ---------------------------------------------------------------------------
__device__ __forceinline__ float bil(const float* __restrict__ img, float x, float y) {
    float x0f = floorf(x), y0f = floorf(y);
    float wx = x - x0f, wy = y - y0f;
    int x0 = (int)x0f, y0 = (int)y0f;
    int x0i = min(max(x0, 0), WI - 1);
    int x1i = min(x0i + 1, WI - 1);
    int y0i = min(max(y0, 0), HI - 1);
    int y1i = min(y0i + 1, HI - 1);
    float v00 = img[y0i * WI + x0i];
    float v01 = img[y0i * WI + x1i];
    float v10 = img[y1i * WI + x0i];
    float v11 = img[y1i * WI + x1i];
    return v00 * (1.0f - wx) * (1.0f - wy) + v01 * wx * (1.0f - wy)
         + v10 * (1.0f - wx) * wy + v11 * wx * wy;
}

__device__ void lk_track(const float* __restrict__ I, const float* __restrict__ J,
                         int lane, float x, float y, float& ox_, float& oy_) {
    int dxs[5], dys[5], rowoff[5];
    bool valid[5];
    float T[5], Gx[5], Gy[5];
#pragma unroll
    for (int i = 0; i < 5; ++i) {
        int k = lane + 64 * i;
        valid[i] = (k < K_LK);
        int kk = valid[i] ? k : 0;
        int dx = kk % 17, dy = kk / 17;
        dxs[i] = dx; dys[i] = dy;
        rowoff[i] = dy * WI + dx;
    }

    float ixf = floorf(x), iyf = floorf(y);
    float wx = x - ixf, wy = y - iyf;
    float w00 = (1.0f - wx) * (1.0f - wy);
    float w01 = wx * (1.0f - wy);
    float w10 = (1.0f - wx) * wy;
    float w11 = wx * wy;

    float a11 = 0.0f, a12 = 0.0f, a22 = 0.0f;
    int fastI = (ixf >= 9.0f) && (ixf <= 245.0f) && (iyf >= 9.0f) && (iyf <= 245.0f);
    fastI = __builtin_amdgcn_readfirstlane(fastI);
    if (fastI) {
        const float* Ib = I + ((int)iyf - 8) * WI + ((int)ixf - 8);
#pragma unroll
        for (int i = 0; i < 5; ++i) {
            const float* p = Ib + rowoff[i];
            f4v r0 = *(const uf4*)(p - 1);        // row dy,   cols dx-1..dx+2
            f4v r1 = *(const uf4*)(p + WI - 1);   // row dy+1, cols dx-1..dx+2
            f2v rm = *(const uf2*)(p - WI);       // row dy-1, cols dx..dx+1
            f2v r2 = *(const uf2*)(p + 2 * WI);   // row dy+2, cols dx..dx+1
            float t   = w00 * r0.y + w01 * r0.z + w10 * r1.y + w11 * r1.z;
            float tx1 = w00 * r0.z + w01 * r0.w + w10 * r1.z + w11 * r1.w;
            float txm = w00 * r0.x + w01 * r0.y + w10 * r1.x + w11 * r1.y;
            float typ = w00 * r1.y + w01 * r1.z + w10 * r2.x + w11 * r2.y;
            float tym = w00 * rm.x + w01 * rm.y + w10 * r0.y + w11 * r0.z;
            float gx = 0.5f * (tx1 - txm);
            float gy = 0.5f * (typ - tym);
            if (!valid[i]) { t = 0.0f; gx = 0.0f; gy = 0.0f; }
            T[i] = t; Gx[i] = gx; Gy[i] = gy;
            a11 += gx * gx; a12 += gx * gy; a22 += gy * gy;
        }
    } else {
#pragma unroll
        for (int i = 0; i < 5; ++i) {
            float fx = x + (float)(dxs[i] - 8);
            float fy = y + (float)(dys[i] - 8);
            float t = bil(I, fx, fy);
            float gx = (bil(I, fx + 1.0f, fy) - bil(I, fx - 1.0f, fy)) * 0.5f;
            float gy = (bil(I, fx, fy + 1.0f) - bil(I, fx, fy - 1.0f)) * 0.5f;
            if (!valid[i]) { t = 0.0f; gx = 0.0f; gy = 0.0f; }
            T[i] = t; Gx[i] = gx; Gy[i] = gy;
            a11 += gx * gx; a12 += gx * gy; a22 += gy * gy;
        }
    }
    for (int m = 32; m; m >>= 1) {
        a11 += __shfl_xor(a11, m, 64);
        a12 += __shfl_xor(a12, m, 64);
        a22 += __shfl_xor(a22, m, 64);
    }
    a11 += 1e-6f;
    a22 += 1e-6f;
    float det = a11 * a22 - a12 * a12;
    float i11 = a22 / det, i12 = -a12 / det, i22 = a11 / det;

    float px = x, py = y;
#pragma unroll 1
    for (int s = 0; s < 10; ++s) {
        float bx = 0.0f, by = 0.0f;
        float jxf = floorf(px), jyf = floorf(py);
        float vx = px - jxf, vy = py - jyf;
        float u00 = (1.0f - vx) * (1.0f - vy);
        float u01 = vx * (1.0f - vy);
        float u10 = (1.0f - vx) * vy;
        float u11 = vx * vy;
        int fastJ = (jxf >= 8.0f) && (jxf <= 246.0f) && (jyf >= 8.0f) && (jyf <= 246.0f);
        fastJ = __builtin_amdgcn_readfirstlane(fastJ);
        if (fastJ) {
            const float* Jb = J + ((int)jyf - 8) * WI + ((int)jxf - 8);
#pragma unroll
            for (int i = 0; i < 5; ++i) {
                const float* p = Jb + rowoff[i];
                f2v q0 = *(const uf2*)(p);
                f2v q1 = *(const uf2*)(p + WI);
                float v = u00 * q0.x + u01 * q0.y + u10 * q1.x + u11 * q1.y;
                float e = T[i] - v;                  // invalid slots: G==0 kills it
                bx += Gx[i] * e;
                by += Gy[i] * e;
            }
        } else {
#pragma unroll
            for (int i = 0; i < 5; ++i) {
                float e = T[i] - bil(J, px + (float)(dxs[i] - 8), py + (float)(dys[i] - 8));
                bx += Gx[i] * e;
                by += Gy[i] * e;
            }
        }
        for (int m = 32; m; m >>= 1) {
            bx += __shfl_xor(bx, m, 64);
            by += __shfl_xor(by, m, 64);
        }
        px += i11 * bx + i12 * by;
        py += i12 * bx + i22 * by;
    }
    ox_ = px;
    oy_ = py;
}

__global__ __launch_bounds__(256) void k_lk(const float* __restrict__ gray,
                                            const float* __restrict__ locs,
                                            float* __restrict__ out_next,
                                            float* __restrict__ out_fb,
                                            float* __restrict__ out_back) {
    int wid = (blockIdx.x * 256 + threadIdx.x) >> 6;
    int lane = threadIdx.x & 63;
    int variant = wid / (NPAIR * NP);
    int r = wid - variant * (NPAIR * NP);
    int pr = r / NP;
    int j = r - pr * NP;
    int b = pr / 15;
    int t = pr - b * 15;
    int n0 = b * 16 + t;
    const float* I = gray + (size_t)n0 * HI * WI;
    const float* J = gray + (size_t)(n0 + 1) * HI * WI;
    int o = (pr * NP + j) * 2;
    if (variant == 0) {
        float x = locs[(n0 * NP + j) * 2 + 0];
        float y = locs[(n0 * NP + j) * 2 + 1];
        float nx, ny;
        lk_track(I, J, lane, x, y, nx, ny);
        if (lane == 0) { out_next[o] = nx; out_next[o + 1] = ny; }
        float fx, fy;
        lk_track(J, I, lane, nx, ny, fx, fy);
        if (lane == 0) { out_fb[o] = fx; out_fb[o + 1] = fy; }
    } else {
        float x = locs[((n0 + 1) * NP + j) * 2 + 0];
        float y = locs[((n0 + 1) * NP + j) * 2 + 1];
        float bx, by;
        lk_track(J, I, lane, x, y, bx, by);
        if (lane == 0) { out_back[o] = bx; out_back[o + 1] = by; }
    }
}

// ---------------------------------------------------------------------------
extern "C" void kernel_launch(void* const* d_in, const int* in_sizes, int n_in,
                              void* d_out, int out_size, void* d_ws, size_t ws_size,
                              hipStream_t stream) {
    const float* inputs = (const float*)d_in[0];
    const float* det_w  = (const float*)d_in[1];
    // det_b (d_in[2]) is softmax-shift-invariant -> unused
    float* out = (float*)d_out;

    float* gray  = (float*)d_ws;                                  // 128*256*256 f32 = 32 MiB
    float* stats = (float*)((char*)d_ws + (size_t)NIMG * HI * WI * 4); // 128*68*16*4 f32

    float* locs   = out;                    // [8,16,68,2]  = 17408
    float* next_p = out + 17408;            // [8,15,68,2]  = 16320
    float* fb_p   = out + 33728;
    float* back_p = out + 50048;

    hipLaunchKernelGGL(k_gray, dim3(2048), dim3(256), 0, stream, inputs, gray);
    hipLaunchKernelGGL(k_conv, dim3(NT, NIMG), dim3(256), 0, stream, inputs, det_w, stats);
    hipLaunchKernelGGL(k_centroid, dim3((NIMG * NP + 255) / 256), dim3(256), 0, stream,
                       stats, locs);
    hipLaunchKernelGGL(k_lk, dim3(2 * NPAIR * NP / 4), dim3(256), 0, stream,
                       gray, locs, next_p, fb_p, back_p);
}